// Round 19
// baseline (153.603 us; speedup 1.0000x reference)
//
#include <hip/hip_runtime.h>
#include <hip/hip_bf16.h>
#include <math.h>

#define NEG_SLOPE 0.2f

typedef short bf16x8 __attribute__((ext_vector_type(8)));
typedef float f32x4 __attribute__((ext_vector_type(4)));
typedef float f32x2 __attribute__((ext_vector_type(2)));
typedef _Float16 f16x2 __attribute__((ext_vector_type(2)));

__device__ __forceinline__ float lrelu(float x) { return fmaxf(x, NEG_SLOPE * x); }

__device__ __forceinline__ ushort f2bf(float f) {
  __hip_bfloat16 b = __float2bfloat16(f);
  return *reinterpret_cast<ushort*>(&b);
}

// fp8 e4m3 (OCP on gfx950) scalar encode: low byte of packed result
__device__ __forceinline__ unsigned char f2fp8(float f) {
  return (unsigned char)(__builtin_amdgcn_cvt_pk_fp8_f32(f, f, 0, false) & 0xFF);
}

// decode 2 packed fp8 -> 2 fp16 (single HW op on gfx950; guarded fallback)
__device__ __forceinline__ f16x2 fp8x2_f16x2(unsigned w) {
#if defined(__has_builtin) && __has_builtin(__builtin_amdgcn_cvt_pk_f16_fp8)
  return __builtin_amdgcn_cvt_pk_f16_fp8((short)w);
#else
  f32x2 p = __builtin_amdgcn_cvt_pk_f32_fp8(w, 0);
  return (f16x2){(_Float16)p[0], (_Float16)p[1]};
#endif
}

// ---------------- prep: Wg[144 cols][128 k] bf16, XOR-swizzled; zeroes deg[] + status[].
__global__ __launch_bounds__(256) void k_prep(
    const float* __restrict__ W1, const float* __restrict__ ats1, const float* __restrict__ atd1,
    ushort* __restrict__ Wg, int* __restrict__ deg, int* __restrict__ status, int N)
{
  int t = blockIdx.x * 256 + threadIdx.x;
  if (t < N) deg[t] = 0;
  if (t < 256) status[t] = 0;
  if (t < 128 * 128) {
    int k = t >> 7, n = t & 127;
    Wg[(size_t)n * 128 + (k ^ ((n & 7) << 3))] = f2bf(W1[t]);
  } else if (t < 128 * 128 + 128 * 16) {
    int tt = t - 128 * 128;
    int k = tt >> 4;          // 0..127
    int c = tt & 15;          // 0..7 -> as, 8..15 -> ad
    int head = c & 7;
    const float* av = (c < 8) ? ats1 : atd1;
    float s = 0.f;
#pragma unroll
    for (int ch = 0; ch < 16; ++ch)
      s += W1[k * 128 + head * 16 + ch] * av[head * 16 + ch];
    int n = 128 + c;
    Wg[(size_t)n * 128 + (k ^ ((n & 7) << 3))] = f2bf(s);
  }
}

// ---------------- h1 = x @ W1 via bf16 MFMA, 64 nodes/block, 4 waves.
// 9 column tiles: 0..7 -> h1f (fp8 e4m3), tile 8 -> as1h (f16) / ad1 (fp32)
__global__ __launch_bounds__(256) void k_gemm1m(
    const float* __restrict__ x, const ushort* __restrict__ Wg,
    unsigned char* __restrict__ h1f, _Float16* __restrict__ as1h,
    float* __restrict__ ad1, int N)
{
  __shared__ ushort Wls[144 * 128];
  const int tid = threadIdx.x;
  const float4* Wg4 = (const float4*)Wg;
  float4* Wl4 = (float4*)Wls;
#pragma unroll
  for (int i = 0; i < 9; ++i) Wl4[tid + i * 256] = Wg4[tid + i * 256];
  __syncthreads();

  const int lane = tid & 63, wid = tid >> 6;
  const int r0 = blockIdx.x * 64 + wid * 16;
  const int lr = lane & 15, kg = lane >> 4;
  int row = r0 + lr; if (row >= N) row = N - 1;
  const float* xr = x + (size_t)row * 128;

  f32x4 acc[9];
#pragma unroll
  for (int i = 0; i < 9; ++i) acc[i] = (f32x4){0.f, 0.f, 0.f, 0.f};

#pragma unroll
  for (int ks = 0; ks < 4; ++ks) {
    int k0 = ks * 32 + kg * 8;
    float4 xa = *(const float4*)(xr + k0);
    float4 xb = *(const float4*)(xr + k0 + 4);
    bf16x8 af;
    af[0] = f2bf(xa.x); af[1] = f2bf(xa.y); af[2] = f2bf(xa.z); af[3] = f2bf(xa.w);
    af[4] = f2bf(xb.x); af[5] = f2bf(xb.y); af[6] = f2bf(xb.z); af[7] = f2bf(xb.w);
#pragma unroll
    for (int nt = 0; nt < 9; ++nt) {
      int n = nt * 16 + lr;
      bf16x8 bfr = *(const bf16x8*)(Wls + n * 128 + (k0 ^ ((n & 7) << 3)));
      acc[nt] = __builtin_amdgcn_mfma_f32_16x16x32_bf16(af, bfr, acc[nt], 0, 0, 0);
    }
  }
  // C layout: col = lane&15, row = (lane>>4)*4 + reg
#pragma unroll
  for (int nt = 0; nt < 8; ++nt) {
#pragma unroll
    for (int i = 0; i < 4; ++i) {
      int r = r0 + kg * 4 + i;
      if (r < N) h1f[(size_t)r * 128 + nt * 16 + lr] = f2fp8(acc[nt][i]);
    }
  }
#pragma unroll
  for (int i = 0; i < 4; ++i) {
    int r = r0 + kg * 4 + i;
    if (r < N) {
      if (lr < 8) as1h[(size_t)r * 8 + lr]    = (_Float16)acc[8][i];
      else        ad1[(size_t)r * 8 + lr - 8] = acc[8][i];
    }
  }
}

// ---------------- CSR build: histogram (+local rank), lookback scan, atomic-free place
__global__ __launch_bounds__(256) void k_hist(const int* __restrict__ ei, int E, int N,
                                              int* __restrict__ deg, int* __restrict__ lrank) {
  int e = blockIdx.x * 256 + threadIdx.x;
  if (e >= E + N) return;
  int d = (e < E) ? ei[E + e] : e - E;
  lrank[e] = atomicAdd(&deg[d], 1);
}

// single-kernel exclusive scan via decoupled lookback (status zeroed by k_prep)
// status[b] = (sum<<2) | flag ; flag: 0=invalid, 1=aggregate, 2=inclusive-prefix
__global__ __launch_bounds__(256) void k_scan_lb(
    const int* __restrict__ deg, int* __restrict__ rowptr,
    int* __restrict__ status, int N)
{
  __shared__ int sc[256];
  __shared__ int sbase;
  const int b = blockIdx.x, t = threadIdx.x;
  const int i0 = b * 512 + 2 * t, i1 = i0 + 1;
  int a  = (i0 < N) ? deg[i0] : 0;
  int bb = (i1 < N) ? deg[i1] : 0;
  int s = a + bb;
  sc[t] = s; __syncthreads();
  int run = s;
  for (int dd = 1; dd < 256; dd <<= 1) {
    int v = (t >= dd) ? sc[t - dd] : 0; __syncthreads();
    run += v; sc[t] = run; __syncthreads();
  }
  const int excl = run - s;
  const int total = sc[255];

  if (t == 0) {
    if (b > 0)
      __hip_atomic_store(&status[b], (total << 2) | 1, __ATOMIC_RELEASE, __HIP_MEMORY_SCOPE_AGENT);
    int base = 0;
    if (b > 0) {
      int j = b - 1;
      while (true) {
        int st = __hip_atomic_load(&status[j], __ATOMIC_ACQUIRE, __HIP_MEMORY_SCOPE_AGENT);
        int fl = st & 3;
        if (fl == 0) continue;
        base += (st >> 2);
        if (fl == 2) break;
        --j;
      }
    }
    __hip_atomic_store(&status[b], ((base + total) << 2) | 2, __ATOMIC_RELEASE, __HIP_MEMORY_SCOPE_AGENT);
    sbase = base;
  }
  __syncthreads();
  const int gb = sbase;
  if (i0 < N) rowptr[i0] = gb + excl;
  if (i1 < N) rowptr[i1] = gb + excl + a;
}

// place: atomic-free scattered write using precomputed local rank
__global__ __launch_bounds__(256) void k_place(const int* __restrict__ ei, int E, int N,
                                               const int* __restrict__ rowptr,
                                               const int* __restrict__ lrank,
                                               int* __restrict__ srt) {
  int e = blockIdx.x * 256 + threadIdx.x;
  if (e >= E + N) return;
  int s, d;
  if (e < E) { s = ei[e]; d = ei[E + e]; } else { s = d = e - E; }
  srt[rowptr[d] + lrank[e]] = s;
}

// ---------------- Fused layer-1: FOUR dst nodes per wave (16 lanes each).
// fp8 h rows (128 B); f16 as values; unroll-4 with prefetch. No cross-group reduction.
__global__ __launch_bounds__(256) void k_agg1f(
    const int* __restrict__ rowptr, const int* __restrict__ deg, const int* __restrict__ srt,
    const _Float16* __restrict__ as1h, const float* __restrict__ ad1,
    const unsigned char* __restrict__ h1f,
    const float* __restrict__ b1, const float* __restrict__ W2,
    const float* __restrict__ ats2, const float* __restrict__ atd2,
    float4* __restrict__ nd2, int N)
{
  const int lane = threadIdx.x & 63;
  const int wid = threadIdx.x >> 6;
  const int grp = lane >> 4, l16 = lane & 15;
  const int d0 = blockIdx.x * 16 + wid * 4 + grp;
  const int d = min(d0, N - 1);
  const int hh = l16 >> 1;                 // head of this lane's 8 channels
  const int hoff = 8 * l16;                // byte offset into fp8 row

  const int start = rowptr[d];
  const int dg = deg[d];
  const int dgm1 = dg - 1;                 // >= 0 (self-loops)
  const int* sp = srt + start;
  const float adh = ad1[d * 8 + hh];

  f16x2 ac0 = {0, 0}, ac1 = {0, 0}, ac2 = {0, 0}, ac3 = {0, 0};
  float sum = 0.f;

#define EDGEACC(hv, ah) { \
    f16x2 av2 = {(ah), (ah)}; \
    ac0 += fp8x2_f16x2((hv).x & 0xffffu) * av2; \
    ac1 += fp8x2_f16x2((hv).x >> 16)     * av2; \
    ac2 += fp8x2_f16x2((hv).y & 0xffffu) * av2; \
    ac3 += fp8x2_f16x2((hv).y >> 16)     * av2; \
  }

  int c = 0;
  int s0 = sp[0];
  int s1 = sp[min(1, dgm1)];
  int s2 = sp[min(2, dgm1)];
  int s3 = sp[min(3, dgm1)];
  while (c < dg) {
    int cn = c + 4;
    int t0 = sp[min(cn,     dgm1)];
    int t1 = sp[min(cn + 1, dgm1)];
    int t2 = sp[min(cn + 2, dgm1)];
    int t3 = sp[min(cn + 3, dgm1)];
    // issue all loads before consumption
    _Float16 a0h = as1h[s0 * 8 + hh];
    uint2 hv0 = *(const uint2*)(h1f + s0 * 128 + hoff);
    _Float16 a1h = as1h[s1 * 8 + hh];
    uint2 hv1 = *(const uint2*)(h1f + s1 * 128 + hoff);
    _Float16 a2h = as1h[s2 * 8 + hh];
    uint2 hv2 = *(const uint2*)(h1f + s2 * 128 + hoff);
    _Float16 a3h = as1h[s3 * 8 + hh];
    uint2 hv3 = *(const uint2*)(h1f + s3 * 128 + hoff);

    float u0f = __expf(lrelu((float)a0h + adh));                  // c < dg guaranteed
    float u1f = (c + 1 < dg) ? __expf(lrelu((float)a1h + adh)) : 0.f;
    float u2f = (c + 2 < dg) ? __expf(lrelu((float)a2h + adh)) : 0.f;
    float u3f = (c + 3 < dg) ? __expf(lrelu((float)a3h + adh)) : 0.f;
    sum += (u0f + u1f) + (u2f + u3f);
    EDGEACC(hv0, (_Float16)u0f);
    EDGEACC(hv1, (_Float16)u1f);
    EDGEACC(hv2, (_Float16)u2f);
    EDGEACC(hv3, (_Float16)u3f);

    c = cn; s0 = t0; s1 = t1; s2 = t2; s3 = t3;
  }
#undef EDGEACC

  // no cross-group reduction: each 16-lane group holds its node's full 128 channels,
  // and each lane's head-sum is complete (all lanes saw all edges).
  float v[8] = {(float)ac0[0], (float)ac0[1], (float)ac1[0], (float)ac1[1],
                (float)ac2[0], (float)ac2[1], (float)ac3[0], (float)ac3[1]};
  const float inv = 1.f / (sum + 1e-16f);

  // epilogue: normalize, +b1, ELU (exp-1), GEMM2 (128->2), layer-2 att dots
  float4 b0 = *(const float4*)(b1 + hoff);
  float4 b4 = *(const float4*)(b1 + hoff + 4);
  v[0] = fmaf(v[0], inv, b0.x); v[1] = fmaf(v[1], inv, b0.y);
  v[2] = fmaf(v[2], inv, b0.z); v[3] = fmaf(v[3], inv, b0.w);
  v[4] = fmaf(v[4], inv, b4.x); v[5] = fmaf(v[5], inv, b4.y);
  v[6] = fmaf(v[6], inv, b4.z); v[7] = fmaf(v[7], inv, b4.w);
#pragma unroll
  for (int j = 0; j < 8; ++j) v[j] = v[j] > 0.f ? v[j] : (__expf(v[j]) - 1.f);

  const float4* W24 = (const float4*)(W2 + 16 * l16);
  float4 w0 = W24[0], w1 = W24[1], w2 = W24[2], w3 = W24[3];
  float p0 = v[0]*w0.x + v[1]*w0.z + v[2]*w1.x + v[3]*w1.z
           + v[4]*w2.x + v[5]*w2.z + v[6]*w3.x + v[7]*w3.z;
  float p1 = v[0]*w0.y + v[1]*w0.w + v[2]*w1.y + v[3]*w1.w
           + v[4]*w2.y + v[5]*w2.w + v[6]*w3.y + v[7]*w3.w;
#pragma unroll
  for (int m = 1; m < 16; m <<= 1) { p0 += __shfl_xor(p0, m); p1 += __shfl_xor(p1, m); }
  if (l16 == 0 && d0 < N) {
    float a2 = p0 * ats2[0] + p1 * ats2[1];
    float dd2 = p0 * atd2[0] + p1 * atd2[1];
    nd2[d0] = make_float4(p0, p1, a2, dd2);
  }
}

// ---------------- Fused layer-2: 16 lanes per dst; one float4 load per edge
__global__ __launch_bounds__(256) void k_agg2f(
    const int* __restrict__ rowptr, const int* __restrict__ deg, const int* __restrict__ srt,
    const float4* __restrict__ nd2, const float* __restrict__ b2,
    float* __restrict__ out, int N)
{
  const int l16 = threadIdx.x & 15;
  const int d = blockIdx.x * 16 + (threadIdx.x >> 4);
  if (d >= N) return;
  const int start = rowptr[d];
  const int dg = deg[d];
  const float adv = nd2[d].w;

  float se = 0.f, a0 = 0.f, a1 = 0.f;
  for (int c = l16; c < dg; c += 16) {
    int s = srt[start + c];
    float4 r = nd2[s];
    float ex = __expf(lrelu(r.z + adv));
    se += ex;
    a0 = fmaf(ex, r.x, a0);
    a1 = fmaf(ex, r.y, a1);
  }
#pragma unroll
  for (int m = 1; m < 16; m <<= 1) {
    se += __shfl_xor(se, m, 16);
    a0 += __shfl_xor(a0, m, 16);
    a1 += __shfl_xor(a1, m, 16);
  }
  if (l16 == 0) {
    float invs = 1.f / (se + 1e-16f);
    out[(size_t)d * 2]     = a0 * invs + b2[0];
    out[(size_t)d * 2 + 1] = a1 * invs + b2[1];
  }
}

extern "C" void kernel_launch(void* const* d_in, const int* in_sizes, int n_in,
                              void* d_out, int out_size, void* d_ws, size_t ws_size,
                              hipStream_t stream) {
  const float* x    = (const float*)d_in[0];
  const int*   ei   = (const int*)d_in[1];
  const float* W1   = (const float*)d_in[2];
  const float* ats1 = (const float*)d_in[3];
  const float* atd1 = (const float*)d_in[4];
  const float* b1   = (const float*)d_in[5];
  const float* W2   = (const float*)d_in[6];
  const float* ats2 = (const float*)d_in[7];
  const float* atd2 = (const float*)d_in[8];
  const float* b2   = (const float*)d_in[9];
  float* out = (float*)d_out;

  const int N  = in_sizes[0] / 128;
  const int E  = in_sizes[1] / 2;
  const int E2 = E + N;
  const int nb = (N + 511) / 512;

  // workspace layout (floats)
  float* ws = (float*)d_ws;
  size_t off = 0;
  unsigned char* h1f = (unsigned char*)(ws + off); off += (size_t)N * 32;  // N*128 fp8
  _Float16* as1h = (_Float16*)(ws + off); off += (size_t)N * 4;            // N*8 f16
  float* ad1 = ws + off; off += (size_t)N * 8;
  float4* nd2 = (float4*)(ws + off); off += (size_t)N * 4;
  int* deg    = (int*)(ws + off); off += (size_t)N;
  int* rowptr = (int*)(ws + off); off += (size_t)N;
  int* status = (int*)(ws + off); off += 256;
  int* srt    = (int*)(ws + off); off += (size_t)E2;
  int* lrank  = (int*)(ws + off); off += (size_t)E2;
  ushort* Wg  = (ushort*)(ws + off); off += 144 * 64;            // 144*128 bf16

  // prep (also zeroes deg + scan status) must run before hist/scan
  const int prep_blocks = max((128 * 128 + 128 * 16 + 255) / 256, (N + 255) / 256);
  k_prep<<<prep_blocks, 256, 0, stream>>>(W1, ats1, atd1, Wg, deg, status, N);

  // layer-1 GEMM
  k_gemm1m<<<(N + 63) / 64, 256, 0, stream>>>(x, Wg, h1f, as1h, ad1, N);

  // CSR build (atomic ranking in hist; single-kernel lookback scan; atomic-free place)
  k_hist<<<(E2 + 255) / 256, 256, 0, stream>>>(ei, E, N, deg, lrank);
  k_scan_lb<<<nb, 256, 0, stream>>>(deg, rowptr, status, N);
  k_place<<<(E2 + 255) / 256, 256, 0, stream>>>(ei, E, N, rowptr, lrank, srt);

  // fused layer-1 softmax+aggregate+ELU+GEMM2+att dots (4 nodes/wave, unroll-4)
  k_agg1f<<<(N + 15) / 16, 256, 0, stream>>>(rowptr, deg, srt, as1h, ad1, h1f,
                                             b1, W2, ats2, atd2, nd2, N);

  // fused layer-2
  k_agg2f<<<(N + 15) / 16, 256, 0, stream>>>(rowptr, deg, srt, nd2, b2, out, N);
}

// Round 20
// 121.466 us; speedup vs baseline: 1.2646x; 1.2646x over previous
//
#include <hip/hip_runtime.h>
#include <hip/hip_bf16.h>
#include <math.h>

#define NEG_SLOPE 0.2f

typedef short bf16x8 __attribute__((ext_vector_type(8)));
typedef float f32x4 __attribute__((ext_vector_type(4)));
typedef float f32x2 __attribute__((ext_vector_type(2)));
typedef _Float16 f16x2 __attribute__((ext_vector_type(2)));

__device__ __forceinline__ float lrelu(float x) { return fmaxf(x, NEG_SLOPE * x); }

__device__ __forceinline__ ushort f2bf(float f) {
  __hip_bfloat16 b = __float2bfloat16(f);
  return *reinterpret_cast<ushort*>(&b);
}

// fp8 e4m3 (OCP on gfx950) scalar encode: low byte of packed result
__device__ __forceinline__ unsigned char f2fp8(float f) {
  return (unsigned char)(__builtin_amdgcn_cvt_pk_fp8_f32(f, f, 0, false) & 0xFF);
}

// decode 2 packed fp8 -> 2 fp16 (single HW op on gfx950; guarded fallback)
__device__ __forceinline__ f16x2 fp8x2_f16x2(unsigned w) {
#if defined(__has_builtin) && __has_builtin(__builtin_amdgcn_cvt_pk_f16_fp8)
  return __builtin_amdgcn_cvt_pk_f16_fp8((short)w);
#else
  f32x2 p = __builtin_amdgcn_cvt_pk_f32_fp8(w, 0);
  return (f16x2){(_Float16)p[0], (_Float16)p[1]};
#endif
}

// ---------------- prep: Wg[144 cols][128 k] bf16, XOR-swizzled; also zeroes deg[].
__global__ __launch_bounds__(256) void k_prep(
    const float* __restrict__ W1, const float* __restrict__ ats1, const float* __restrict__ atd1,
    ushort* __restrict__ Wg, int* __restrict__ deg, int N)
{
  int t = blockIdx.x * 256 + threadIdx.x;
  if (t < N) deg[t] = 0;
  if (t < 128 * 128) {
    int k = t >> 7, n = t & 127;
    Wg[(size_t)n * 128 + (k ^ ((n & 7) << 3))] = f2bf(W1[t]);
  } else if (t < 128 * 128 + 128 * 16) {
    int tt = t - 128 * 128;
    int k = tt >> 4;          // 0..127
    int c = tt & 15;          // 0..7 -> as, 8..15 -> ad
    int head = c & 7;
    const float* av = (c < 8) ? ats1 : atd1;
    float s = 0.f;
#pragma unroll
    for (int ch = 0; ch < 16; ++ch)
      s += W1[k * 128 + head * 16 + ch] * av[head * 16 + ch];
    int n = 128 + c;
    Wg[(size_t)n * 128 + (k ^ ((n & 7) << 3))] = f2bf(s);
  }
}

// ---------------- h1 = x @ W1 via bf16 MFMA, 64 nodes/block, 4 waves.
// 9 column tiles: 0..7 -> h1f (fp8 e4m3), tile 8 -> as1h (f16) / ad1 (fp32)
__global__ __launch_bounds__(256) void k_gemm1m(
    const float* __restrict__ x, const ushort* __restrict__ Wg,
    unsigned char* __restrict__ h1f, _Float16* __restrict__ as1h,
    float* __restrict__ ad1, int N)
{
  __shared__ ushort Wls[144 * 128];
  const int tid = threadIdx.x;
  const float4* Wg4 = (const float4*)Wg;
  float4* Wl4 = (float4*)Wls;
#pragma unroll
  for (int i = 0; i < 9; ++i) Wl4[tid + i * 256] = Wg4[tid + i * 256];
  __syncthreads();

  const int lane = tid & 63, wid = tid >> 6;
  const int r0 = blockIdx.x * 64 + wid * 16;
  const int lr = lane & 15, kg = lane >> 4;
  int row = r0 + lr; if (row >= N) row = N - 1;
  const float* xr = x + (size_t)row * 128;

  f32x4 acc[9];
#pragma unroll
  for (int i = 0; i < 9; ++i) acc[i] = (f32x4){0.f, 0.f, 0.f, 0.f};

#pragma unroll
  for (int ks = 0; ks < 4; ++ks) {
    int k0 = ks * 32 + kg * 8;
    float4 xa = *(const float4*)(xr + k0);
    float4 xb = *(const float4*)(xr + k0 + 4);
    bf16x8 af;
    af[0] = f2bf(xa.x); af[1] = f2bf(xa.y); af[2] = f2bf(xa.z); af[3] = f2bf(xa.w);
    af[4] = f2bf(xb.x); af[5] = f2bf(xb.y); af[6] = f2bf(xb.z); af[7] = f2bf(xb.w);
#pragma unroll
    for (int nt = 0; nt < 9; ++nt) {
      int n = nt * 16 + lr;
      bf16x8 bfr = *(const bf16x8*)(Wls + n * 128 + (k0 ^ ((n & 7) << 3)));
      acc[nt] = __builtin_amdgcn_mfma_f32_16x16x32_bf16(af, bfr, acc[nt], 0, 0, 0);
    }
  }
  // C layout: col = lane&15, row = (lane>>4)*4 + reg
#pragma unroll
  for (int nt = 0; nt < 8; ++nt) {
#pragma unroll
    for (int i = 0; i < 4; ++i) {
      int r = r0 + kg * 4 + i;
      if (r < N) h1f[(size_t)r * 128 + nt * 16 + lr] = f2fp8(acc[nt][i]);
    }
  }
#pragma unroll
  for (int i = 0; i < 4; ++i) {
    int r = r0 + kg * 4 + i;
    if (r < N) {
      if (lr < 8) as1h[(size_t)r * 8 + lr]    = (_Float16)acc[8][i];
      else        ad1[(size_t)r * 8 + lr - 8] = acc[8][i];
    }
  }
}

// ---------------- CSR build: histogram (+local rank), 2-level scan, atomic-free place
__global__ __launch_bounds__(256) void k_hist(const int* __restrict__ ei, int E, int N,
                                              int* __restrict__ deg, int* __restrict__ lrank) {
  int e = blockIdx.x * 256 + threadIdx.x;
  if (e >= E + N) return;
  int d = (e < E) ? ei[E + e] : e - E;
  lrank[e] = atomicAdd(&deg[d], 1);
}

__global__ __launch_bounds__(256) void k_scan1(const int* __restrict__ deg,
                                               int* __restrict__ rowptr,
                                               int* __restrict__ bsum, int N) {
  __shared__ int sc[256];
  int b = blockIdx.x, t = threadIdx.x;
  int i0 = b * 512 + 2 * t, i1 = i0 + 1;
  int a = (i0 < N) ? deg[i0] : 0;
  int bb = (i1 < N) ? deg[i1] : 0;
  int s = a + bb;
  sc[t] = s; __syncthreads();
  int run = s;
  for (int dd = 1; dd < 256; dd <<= 1) {
    int v = (t >= dd) ? sc[t - dd] : 0; __syncthreads();
    run += v; sc[t] = run; __syncthreads();
  }
  int excl = run - s;
  if (i0 < N) rowptr[i0] = excl;
  if (i1 < N) rowptr[i1] = excl + a;
  if (t == 255) bsum[b] = run;
}

__global__ __launch_bounds__(256) void k_scan2(int* __restrict__ bsum, int nb) {
  __shared__ int sc[256];
  int t = threadIdx.x;
  int s = (t < nb) ? bsum[t] : 0;
  sc[t] = s; __syncthreads();
  int run = s;
  for (int dd = 1; dd < 256; dd <<= 1) {
    int v = (t >= dd) ? sc[t - dd] : 0; __syncthreads();
    run += v; sc[t] = run; __syncthreads();
  }
  if (t < nb) bsum[t] = run - s;
}

__global__ __launch_bounds__(256) void k_scan3(int* __restrict__ rowptr,
                                               const int* __restrict__ bsum, int N) {
  int i = blockIdx.x * 256 + threadIdx.x;
  if (i >= N) return;
  rowptr[i] += bsum[i >> 9];
}

// place: atomic-free scattered write using precomputed local rank
__global__ __launch_bounds__(256) void k_place(const int* __restrict__ ei, int E, int N,
                                               const int* __restrict__ rowptr,
                                               const int* __restrict__ lrank,
                                               int* __restrict__ srt) {
  int e = blockIdx.x * 256 + threadIdx.x;
  if (e >= E + N) return;
  int s, d;
  if (e < E) { s = ei[e]; d = ei[E + e]; } else { s = d = e - E; }
  srt[rowptr[d] + lrank[e]] = s;
}

// ---------------- Fused layer-1: FOUR dst nodes per wave (16 lanes each).
// fp8 h rows (128 B); f16 as values; unroll-4 with prefetch. No cross-group reduction.
__global__ __launch_bounds__(256) void k_agg1f(
    const int* __restrict__ rowptr, const int* __restrict__ deg, const int* __restrict__ srt,
    const _Float16* __restrict__ as1h, const float* __restrict__ ad1,
    const unsigned char* __restrict__ h1f,
    const float* __restrict__ b1, const float* __restrict__ W2,
    const float* __restrict__ ats2, const float* __restrict__ atd2,
    float4* __restrict__ nd2, int N)
{
  const int lane = threadIdx.x & 63;
  const int wid = threadIdx.x >> 6;
  const int grp = lane >> 4, l16 = lane & 15;
  const int d0 = blockIdx.x * 16 + wid * 4 + grp;
  const int d = min(d0, N - 1);
  const int hh = l16 >> 1;                 // head of this lane's 8 channels
  const int hoff = 8 * l16;                // byte offset into fp8 row

  const int start = rowptr[d];
  const int dg = deg[d];
  const int dgm1 = dg - 1;                 // >= 0 (self-loops)
  const int* sp = srt + start;
  const float adh = ad1[d * 8 + hh];

  f16x2 ac0 = {0, 0}, ac1 = {0, 0}, ac2 = {0, 0}, ac3 = {0, 0};
  float sum = 0.f;

#define EDGEACC(hv, ah) { \
    f16x2 av2 = {(ah), (ah)}; \
    ac0 += fp8x2_f16x2((hv).x & 0xffffu) * av2; \
    ac1 += fp8x2_f16x2((hv).x >> 16)     * av2; \
    ac2 += fp8x2_f16x2((hv).y & 0xffffu) * av2; \
    ac3 += fp8x2_f16x2((hv).y >> 16)     * av2; \
  }

  int c = 0;
  int s0 = sp[0];
  int s1 = sp[min(1, dgm1)];
  int s2 = sp[min(2, dgm1)];
  int s3 = sp[min(3, dgm1)];
  while (c < dg) {
    int cn = c + 4;
    int t0 = sp[min(cn,     dgm1)];
    int t1 = sp[min(cn + 1, dgm1)];
    int t2 = sp[min(cn + 2, dgm1)];
    int t3 = sp[min(cn + 3, dgm1)];
    // issue all loads before consumption
    _Float16 a0h = as1h[s0 * 8 + hh];
    uint2 hv0 = *(const uint2*)(h1f + s0 * 128 + hoff);
    _Float16 a1h = as1h[s1 * 8 + hh];
    uint2 hv1 = *(const uint2*)(h1f + s1 * 128 + hoff);
    _Float16 a2h = as1h[s2 * 8 + hh];
    uint2 hv2 = *(const uint2*)(h1f + s2 * 128 + hoff);
    _Float16 a3h = as1h[s3 * 8 + hh];
    uint2 hv3 = *(const uint2*)(h1f + s3 * 128 + hoff);

    float u0f = __expf(lrelu((float)a0h + adh));                  // c < dg guaranteed
    float u1f = (c + 1 < dg) ? __expf(lrelu((float)a1h + adh)) : 0.f;
    float u2f = (c + 2 < dg) ? __expf(lrelu((float)a2h + adh)) : 0.f;
    float u3f = (c + 3 < dg) ? __expf(lrelu((float)a3h + adh)) : 0.f;
    sum += (u0f + u1f) + (u2f + u3f);
    EDGEACC(hv0, (_Float16)u0f);
    EDGEACC(hv1, (_Float16)u1f);
    EDGEACC(hv2, (_Float16)u2f);
    EDGEACC(hv3, (_Float16)u3f);

    c = cn; s0 = t0; s1 = t1; s2 = t2; s3 = t3;
  }
#undef EDGEACC

  // no cross-group reduction: each 16-lane group holds its node's full 128 channels,
  // and each lane's head-sum is complete (all lanes saw all edges).
  float v[8] = {(float)ac0[0], (float)ac0[1], (float)ac1[0], (float)ac1[1],
                (float)ac2[0], (float)ac2[1], (float)ac3[0], (float)ac3[1]};
  const float inv = 1.f / (sum + 1e-16f);

  // epilogue: normalize, +b1, ELU (exp-1), GEMM2 (128->2), layer-2 att dots
  float4 b0 = *(const float4*)(b1 + hoff);
  float4 b4 = *(const float4*)(b1 + hoff + 4);
  v[0] = fmaf(v[0], inv, b0.x); v[1] = fmaf(v[1], inv, b0.y);
  v[2] = fmaf(v[2], inv, b0.z); v[3] = fmaf(v[3], inv, b0.w);
  v[4] = fmaf(v[4], inv, b4.x); v[5] = fmaf(v[5], inv, b4.y);
  v[6] = fmaf(v[6], inv, b4.z); v[7] = fmaf(v[7], inv, b4.w);
#pragma unroll
  for (int j = 0; j < 8; ++j) v[j] = v[j] > 0.f ? v[j] : (__expf(v[j]) - 1.f);

  const float4* W24 = (const float4*)(W2 + 16 * l16);
  float4 w0 = W24[0], w1 = W24[1], w2 = W24[2], w3 = W24[3];
  float p0 = v[0]*w0.x + v[1]*w0.z + v[2]*w1.x + v[3]*w1.z
           + v[4]*w2.x + v[5]*w2.z + v[6]*w3.x + v[7]*w3.z;
  float p1 = v[0]*w0.y + v[1]*w0.w + v[2]*w1.y + v[3]*w1.w
           + v[4]*w2.y + v[5]*w2.w + v[6]*w3.y + v[7]*w3.w;
#pragma unroll
  for (int m = 1; m < 16; m <<= 1) { p0 += __shfl_xor(p0, m); p1 += __shfl_xor(p1, m); }
  if (l16 == 0 && d0 < N) {
    float a2 = p0 * ats2[0] + p1 * ats2[1];
    float dd2 = p0 * atd2[0] + p1 * atd2[1];
    nd2[d0] = make_float4(p0, p1, a2, dd2);
  }
}

// ---------------- Fused layer-2: 16 lanes per dst; one float4 load per edge
__global__ __launch_bounds__(256) void k_agg2f(
    const int* __restrict__ rowptr, const int* __restrict__ deg, const int* __restrict__ srt,
    const float4* __restrict__ nd2, const float* __restrict__ b2,
    float* __restrict__ out, int N)
{
  const int l16 = threadIdx.x & 15;
  const int d = blockIdx.x * 16 + (threadIdx.x >> 4);
  if (d >= N) return;
  const int start = rowptr[d];
  const int dg = deg[d];
  const float adv = nd2[d].w;

  float se = 0.f, a0 = 0.f, a1 = 0.f;
  for (int c = l16; c < dg; c += 16) {
    int s = srt[start + c];
    float4 r = nd2[s];
    float ex = __expf(lrelu(r.z + adv));
    se += ex;
    a0 = fmaf(ex, r.x, a0);
    a1 = fmaf(ex, r.y, a1);
  }
#pragma unroll
  for (int m = 1; m < 16; m <<= 1) {
    se += __shfl_xor(se, m, 16);
    a0 += __shfl_xor(a0, m, 16);
    a1 += __shfl_xor(a1, m, 16);
  }
  if (l16 == 0) {
    float invs = 1.f / (se + 1e-16f);
    out[(size_t)d * 2]     = a0 * invs + b2[0];
    out[(size_t)d * 2 + 1] = a1 * invs + b2[1];
  }
}

extern "C" void kernel_launch(void* const* d_in, const int* in_sizes, int n_in,
                              void* d_out, int out_size, void* d_ws, size_t ws_size,
                              hipStream_t stream) {
  const float* x    = (const float*)d_in[0];
  const int*   ei   = (const int*)d_in[1];
  const float* W1   = (const float*)d_in[2];
  const float* ats1 = (const float*)d_in[3];
  const float* atd1 = (const float*)d_in[4];
  const float* b1   = (const float*)d_in[5];
  const float* W2   = (const float*)d_in[6];
  const float* ats2 = (const float*)d_in[7];
  const float* atd2 = (const float*)d_in[8];
  const float* b2   = (const float*)d_in[9];
  float* out = (float*)d_out;

  const int N  = in_sizes[0] / 128;
  const int E  = in_sizes[1] / 2;
  const int E2 = E + N;
  const int nb = (N + 511) / 512;

  // workspace layout (floats)
  float* ws = (float*)d_ws;
  size_t off = 0;
  unsigned char* h1f = (unsigned char*)(ws + off); off += (size_t)N * 32;  // N*128 fp8
  _Float16* as1h = (_Float16*)(ws + off); off += (size_t)N * 4;            // N*8 f16
  float* ad1 = ws + off; off += (size_t)N * 8;
  float4* nd2 = (float4*)(ws + off); off += (size_t)N * 4;
  int* deg    = (int*)(ws + off); off += (size_t)N;
  int* rowptr = (int*)(ws + off); off += (size_t)N;
  int* bsum   = (int*)(ws + off); off += 256;
  int* srt    = (int*)(ws + off); off += (size_t)E2;
  int* lrank  = (int*)(ws + off); off += (size_t)E2;
  ushort* Wg  = (ushort*)(ws + off); off += 144 * 64;            // 144*128 bf16

  // prep (also zeroes deg) must run before hist
  const int prep_blocks = max((128 * 128 + 128 * 16 + 255) / 256, (N + 255) / 256);
  k_prep<<<prep_blocks, 256, 0, stream>>>(W1, ats1, atd1, Wg, deg, N);

  // layer-1 GEMM
  k_gemm1m<<<(N + 63) / 64, 256, 0, stream>>>(x, Wg, h1f, as1h, ad1, N);

  // CSR build (atomic ranking in hist; 3-kernel scan; atomic-free place)
  k_hist<<<(E2 + 255) / 256, 256, 0, stream>>>(ei, E, N, deg, lrank);
  k_scan1<<<nb, 256, 0, stream>>>(deg, rowptr, bsum, N);
  k_scan2<<<1, 256, 0, stream>>>(bsum, nb);
  k_scan3<<<(N + 255) / 256, 256, 0, stream>>>(rowptr, bsum, N);
  k_place<<<(E2 + 255) / 256, 256, 0, stream>>>(ei, E, N, rowptr, lrank, srt);

  // fused layer-1 softmax+aggregate+ELU+GEMM2+att dots (4 nodes/wave, unroll-4)
  k_agg1f<<<(N + 15) / 16, 256, 0, stream>>>(rowptr, deg, srt, as1h, ad1, h1f,
                                             b1, W2, ats2, atd2, nd2, N);

  // fused layer-2
  k_agg2f<<<(N + 15) / 16, 256, 0, stream>>>(rowptr, deg, srt, nd2, b2, out, N);
}

// Round 21
// 113.182 us; speedup vs baseline: 1.3571x; 1.0732x over previous
//
#include <hip/hip_runtime.h>
#include <hip/hip_bf16.h>
#include <math.h>

#define NEG_SLOPE 0.2f

typedef short bf16x8 __attribute__((ext_vector_type(8)));
typedef float f32x4 __attribute__((ext_vector_type(4)));
typedef float f32x2 __attribute__((ext_vector_type(2)));
typedef _Float16 f16x2 __attribute__((ext_vector_type(2)));

__device__ __forceinline__ float lrelu(float x) { return fmaxf(x, NEG_SLOPE * x); }

__device__ __forceinline__ ushort f2bf(float f) {
  __hip_bfloat16 b = __float2bfloat16(f);
  return *reinterpret_cast<ushort*>(&b);
}

// fp8 e4m3 (OCP on gfx950) scalar encode: low byte of packed result
__device__ __forceinline__ unsigned char f2fp8(float f) {
  return (unsigned char)(__builtin_amdgcn_cvt_pk_fp8_f32(f, f, 0, false) & 0xFF);
}

// decode 2 packed fp8 -> 2 fp16 (single HW op on gfx950; guarded fallback)
__device__ __forceinline__ f16x2 fp8x2_f16x2(unsigned w) {
#if defined(__has_builtin) && __has_builtin(__builtin_amdgcn_cvt_pk_f16_fp8)
  return __builtin_amdgcn_cvt_pk_f16_fp8((short)w);
#else
  f32x2 p = __builtin_amdgcn_cvt_pk_f32_fp8(w, 0);
  return (f16x2){(_Float16)p[0], (_Float16)p[1]};
#endif
}

// ---------------- prep: Wg[144 cols][128 k] bf16, XOR-swizzled; also zeroes deg[].
__global__ __launch_bounds__(256) void k_prep(
    const float* __restrict__ W1, const float* __restrict__ ats1, const float* __restrict__ atd1,
    ushort* __restrict__ Wg, int* __restrict__ deg, int N)
{
  int t = blockIdx.x * 256 + threadIdx.x;
  if (t < N) deg[t] = 0;
  if (t < 128 * 128) {
    int k = t >> 7, n = t & 127;
    Wg[(size_t)n * 128 + (k ^ ((n & 7) << 3))] = f2bf(W1[t]);
  } else if (t < 128 * 128 + 128 * 16) {
    int tt = t - 128 * 128;
    int k = tt >> 4;          // 0..127
    int c = tt & 15;          // 0..7 -> as, 8..15 -> ad
    int head = c & 7;
    const float* av = (c < 8) ? ats1 : atd1;
    float s = 0.f;
#pragma unroll
    for (int ch = 0; ch < 16; ++ch)
      s += W1[k * 128 + head * 16 + ch] * av[head * 16 + ch];
    int n = 128 + c;
    Wg[(size_t)n * 128 + (k ^ ((n & 7) << 3))] = f2bf(s);
  }
}

// ---------------- Heterogeneous: blocks [0,GB) = GEMM1 (bf16 MFMA, fp8/f16 outputs);
// blocks [GB,..) = edge histogram + local rank. Independent work, one launch.
__global__ __launch_bounds__(256) void k_gh(
    const float* __restrict__ x, const ushort* __restrict__ Wg,
    unsigned char* __restrict__ h1f, _Float16* __restrict__ as1h,
    float* __restrict__ ad1, int N, int GB,
    const int* __restrict__ ei, int E,
    int* __restrict__ deg, int* __restrict__ lrank)
{
  __shared__ ushort Wls[144 * 128];
  const int tid = threadIdx.x;

  if (blockIdx.x >= GB) {
    // ---- histogram part (uniform branch; LDS unused)
    int e = (blockIdx.x - GB) * 256 + tid;
    if (e < E + N) {
      int d = (e < E) ? ei[E + e] : e - E;
      lrank[e] = atomicAdd(&deg[d], 1);
    }
    return;
  }

  // ---- GEMM part
  const float4* Wg4 = (const float4*)Wg;
  float4* Wl4 = (float4*)Wls;
#pragma unroll
  for (int i = 0; i < 9; ++i) Wl4[tid + i * 256] = Wg4[tid + i * 256];
  __syncthreads();

  const int lane = tid & 63, wid = tid >> 6;
  const int r0 = blockIdx.x * 64 + wid * 16;
  const int lr = lane & 15, kg = lane >> 4;
  int row = r0 + lr; if (row >= N) row = N - 1;
  const float* xr = x + (size_t)row * 128;

  f32x4 acc[9];
#pragma unroll
  for (int i = 0; i < 9; ++i) acc[i] = (f32x4){0.f, 0.f, 0.f, 0.f};

#pragma unroll
  for (int ks = 0; ks < 4; ++ks) {
    int k0 = ks * 32 + kg * 8;
    float4 xa = *(const float4*)(xr + k0);
    float4 xb = *(const float4*)(xr + k0 + 4);
    bf16x8 af;
    af[0] = f2bf(xa.x); af[1] = f2bf(xa.y); af[2] = f2bf(xa.z); af[3] = f2bf(xa.w);
    af[4] = f2bf(xb.x); af[5] = f2bf(xb.y); af[6] = f2bf(xb.z); af[7] = f2bf(xb.w);
#pragma unroll
    for (int nt = 0; nt < 9; ++nt) {
      int n = nt * 16 + lr;
      bf16x8 bfr = *(const bf16x8*)(Wls + n * 128 + (k0 ^ ((n & 7) << 3)));
      acc[nt] = __builtin_amdgcn_mfma_f32_16x16x32_bf16(af, bfr, acc[nt], 0, 0, 0);
    }
  }
  // C layout: col = lane&15, row = (lane>>4)*4 + reg
#pragma unroll
  for (int nt = 0; nt < 8; ++nt) {
#pragma unroll
    for (int i = 0; i < 4; ++i) {
      int r = r0 + kg * 4 + i;
      if (r < N) h1f[(size_t)r * 128 + nt * 16 + lr] = f2fp8(acc[nt][i]);
    }
  }
#pragma unroll
  for (int i = 0; i < 4; ++i) {
    int r = r0 + kg * 4 + i;
    if (r < N) {
      if (lr < 8) as1h[(size_t)r * 8 + lr]    = (_Float16)acc[8][i];
      else        ad1[(size_t)r * 8 + lr - 8] = acc[8][i];
    }
  }
}

// ---------------- CSR scan (3-kernel, proven) + atomic-free place
__global__ __launch_bounds__(256) void k_scan1(const int* __restrict__ deg,
                                               int* __restrict__ rowptr,
                                               int* __restrict__ bsum, int N) {
  __shared__ int sc[256];
  int b = blockIdx.x, t = threadIdx.x;
  int i0 = b * 512 + 2 * t, i1 = i0 + 1;
  int a = (i0 < N) ? deg[i0] : 0;
  int bb = (i1 < N) ? deg[i1] : 0;
  int s = a + bb;
  sc[t] = s; __syncthreads();
  int run = s;
  for (int dd = 1; dd < 256; dd <<= 1) {
    int v = (t >= dd) ? sc[t - dd] : 0; __syncthreads();
    run += v; sc[t] = run; __syncthreads();
  }
  int excl = run - s;
  if (i0 < N) rowptr[i0] = excl;
  if (i1 < N) rowptr[i1] = excl + a;
  if (t == 255) bsum[b] = run;
}

__global__ __launch_bounds__(256) void k_scan2(int* __restrict__ bsum, int nb) {
  __shared__ int sc[256];
  int t = threadIdx.x;
  int s = (t < nb) ? bsum[t] : 0;
  sc[t] = s; __syncthreads();
  int run = s;
  for (int dd = 1; dd < 256; dd <<= 1) {
    int v = (t >= dd) ? sc[t - dd] : 0; __syncthreads();
    run += v; sc[t] = run; __syncthreads();
  }
  if (t < nb) bsum[t] = run - s;
}

__global__ __launch_bounds__(256) void k_scan3(int* __restrict__ rowptr,
                                               const int* __restrict__ bsum, int N) {
  int i = blockIdx.x * 256 + threadIdx.x;
  if (i >= N) return;
  rowptr[i] += bsum[i >> 9];
}

// place: atomic-free scattered write using precomputed local rank
__global__ __launch_bounds__(256) void k_place(const int* __restrict__ ei, int E, int N,
                                               const int* __restrict__ rowptr,
                                               const int* __restrict__ lrank,
                                               int* __restrict__ srt) {
  int e = blockIdx.x * 256 + threadIdx.x;
  if (e >= E + N) return;
  int s, d;
  if (e < E) { s = ei[e]; d = ei[E + e]; } else { s = d = e - E; }
  srt[rowptr[d] + lrank[e]] = s;
}

// ---------------- Fused layer-1: FOUR dst nodes per wave (16 lanes each).
// fp8 h rows (128 B); f16 as values; unroll-4 with prefetch. No cross-group reduction.
__global__ __launch_bounds__(256) void k_agg1f(
    const int* __restrict__ rowptr, const int* __restrict__ deg, const int* __restrict__ srt,
    const _Float16* __restrict__ as1h, const float* __restrict__ ad1,
    const unsigned char* __restrict__ h1f,
    const float* __restrict__ b1, const float* __restrict__ W2,
    const float* __restrict__ ats2, const float* __restrict__ atd2,
    float4* __restrict__ nd2, int N)
{
  const int lane = threadIdx.x & 63;
  const int wid = threadIdx.x >> 6;
  const int grp = lane >> 4, l16 = lane & 15;
  const int d0 = blockIdx.x * 16 + wid * 4 + grp;
  const int d = min(d0, N - 1);
  const int hh = l16 >> 1;                 // head of this lane's 8 channels
  const int hoff = 8 * l16;                // byte offset into fp8 row

  const int start = rowptr[d];
  const int dg = deg[d];
  const int dgm1 = dg - 1;                 // >= 0 (self-loops)
  const int* sp = srt + start;
  const float adh = ad1[d * 8 + hh];

  f16x2 ac0 = {0, 0}, ac1 = {0, 0}, ac2 = {0, 0}, ac3 = {0, 0};
  float sum = 0.f;

#define EDGEACC(hv, ah) { \
    f16x2 av2 = {(ah), (ah)}; \
    ac0 += fp8x2_f16x2((hv).x & 0xffffu) * av2; \
    ac1 += fp8x2_f16x2((hv).x >> 16)     * av2; \
    ac2 += fp8x2_f16x2((hv).y & 0xffffu) * av2; \
    ac3 += fp8x2_f16x2((hv).y >> 16)     * av2; \
  }

  int c = 0;
  int s0 = sp[0];
  int s1 = sp[min(1, dgm1)];
  int s2 = sp[min(2, dgm1)];
  int s3 = sp[min(3, dgm1)];
  while (c < dg) {
    int cn = c + 4;
    int t0 = sp[min(cn,     dgm1)];
    int t1 = sp[min(cn + 1, dgm1)];
    int t2 = sp[min(cn + 2, dgm1)];
    int t3 = sp[min(cn + 3, dgm1)];
    // issue all loads before consumption
    _Float16 a0h = as1h[s0 * 8 + hh];
    uint2 hv0 = *(const uint2*)(h1f + s0 * 128 + hoff);
    _Float16 a1h = as1h[s1 * 8 + hh];
    uint2 hv1 = *(const uint2*)(h1f + s1 * 128 + hoff);
    _Float16 a2h = as1h[s2 * 8 + hh];
    uint2 hv2 = *(const uint2*)(h1f + s2 * 128 + hoff);
    _Float16 a3h = as1h[s3 * 8 + hh];
    uint2 hv3 = *(const uint2*)(h1f + s3 * 128 + hoff);

    float u0f = __expf(lrelu((float)a0h + adh));                  // c < dg guaranteed
    float u1f = (c + 1 < dg) ? __expf(lrelu((float)a1h + adh)) : 0.f;
    float u2f = (c + 2 < dg) ? __expf(lrelu((float)a2h + adh)) : 0.f;
    float u3f = (c + 3 < dg) ? __expf(lrelu((float)a3h + adh)) : 0.f;
    sum += (u0f + u1f) + (u2f + u3f);
    EDGEACC(hv0, (_Float16)u0f);
    EDGEACC(hv1, (_Float16)u1f);
    EDGEACC(hv2, (_Float16)u2f);
    EDGEACC(hv3, (_Float16)u3f);

    c = cn; s0 = t0; s1 = t1; s2 = t2; s3 = t3;
  }
#undef EDGEACC

  // no cross-group reduction: each 16-lane group holds its node's full 128 channels,
  // and each lane's head-sum is complete (all lanes saw all edges).
  float v[8] = {(float)ac0[0], (float)ac0[1], (float)ac1[0], (float)ac1[1],
                (float)ac2[0], (float)ac2[1], (float)ac3[0], (float)ac3[1]};
  const float inv = 1.f / (sum + 1e-16f);

  // epilogue: normalize, +b1, ELU (exp-1), GEMM2 (128->2), layer-2 att dots
  float4 b0 = *(const float4*)(b1 + hoff);
  float4 b4 = *(const float4*)(b1 + hoff + 4);
  v[0] = fmaf(v[0], inv, b0.x); v[1] = fmaf(v[1], inv, b0.y);
  v[2] = fmaf(v[2], inv, b0.z); v[3] = fmaf(v[3], inv, b0.w);
  v[4] = fmaf(v[4], inv, b4.x); v[5] = fmaf(v[5], inv, b4.y);
  v[6] = fmaf(v[6], inv, b4.z); v[7] = fmaf(v[7], inv, b4.w);
#pragma unroll
  for (int j = 0; j < 8; ++j) v[j] = v[j] > 0.f ? v[j] : (__expf(v[j]) - 1.f);

  const float4* W24 = (const float4*)(W2 + 16 * l16);
  float4 w0 = W24[0], w1 = W24[1], w2 = W24[2], w3 = W24[3];
  float p0 = v[0]*w0.x + v[1]*w0.z + v[2]*w1.x + v[3]*w1.z
           + v[4]*w2.x + v[5]*w2.z + v[6]*w3.x + v[7]*w3.z;
  float p1 = v[0]*w0.y + v[1]*w0.w + v[2]*w1.y + v[3]*w1.w
           + v[4]*w2.y + v[5]*w2.w + v[6]*w3.y + v[7]*w3.w;
#pragma unroll
  for (int m = 1; m < 16; m <<= 1) { p0 += __shfl_xor(p0, m); p1 += __shfl_xor(p1, m); }
  if (l16 == 0 && d0 < N) {
    float a2 = p0 * ats2[0] + p1 * ats2[1];
    float dd2 = p0 * atd2[0] + p1 * atd2[1];
    nd2[d0] = make_float4(p0, p1, a2, dd2);
  }
}

// ---------------- Fused layer-2: 16 lanes per dst; one float4 load per edge
__global__ __launch_bounds__(256) void k_agg2f(
    const int* __restrict__ rowptr, const int* __restrict__ deg, const int* __restrict__ srt,
    const float4* __restrict__ nd2, const float* __restrict__ b2,
    float* __restrict__ out, int N)
{
  const int l16 = threadIdx.x & 15;
  const int d = blockIdx.x * 16 + (threadIdx.x >> 4);
  if (d >= N) return;
  const int start = rowptr[d];
  const int dg = deg[d];
  const float adv = nd2[d].w;

  float se = 0.f, a0 = 0.f, a1 = 0.f;
  for (int c = l16; c < dg; c += 16) {
    int s = srt[start + c];
    float4 r = nd2[s];
    float ex = __expf(lrelu(r.z + adv));
    se += ex;
    a0 = fmaf(ex, r.x, a0);
    a1 = fmaf(ex, r.y, a1);
  }
#pragma unroll
  for (int m = 1; m < 16; m <<= 1) {
    se += __shfl_xor(se, m, 16);
    a0 += __shfl_xor(a0, m, 16);
    a1 += __shfl_xor(a1, m, 16);
  }
  if (l16 == 0) {
    float invs = 1.f / (se + 1e-16f);
    out[(size_t)d * 2]     = a0 * invs + b2[0];
    out[(size_t)d * 2 + 1] = a1 * invs + b2[1];
  }
}

extern "C" void kernel_launch(void* const* d_in, const int* in_sizes, int n_in,
                              void* d_out, int out_size, void* d_ws, size_t ws_size,
                              hipStream_t stream) {
  const float* x    = (const float*)d_in[0];
  const int*   ei   = (const int*)d_in[1];
  const float* W1   = (const float*)d_in[2];
  const float* ats1 = (const float*)d_in[3];
  const float* atd1 = (const float*)d_in[4];
  const float* b1   = (const float*)d_in[5];
  const float* W2   = (const float*)d_in[6];
  const float* ats2 = (const float*)d_in[7];
  const float* atd2 = (const float*)d_in[8];
  const float* b2   = (const float*)d_in[9];
  float* out = (float*)d_out;

  const int N  = in_sizes[0] / 128;
  const int E  = in_sizes[1] / 2;
  const int E2 = E + N;
  const int nb = (N + 511) / 512;

  // workspace layout (floats)
  float* ws = (float*)d_ws;
  size_t off = 0;
  unsigned char* h1f = (unsigned char*)(ws + off); off += (size_t)N * 32;  // N*128 fp8
  _Float16* as1h = (_Float16*)(ws + off); off += (size_t)N * 4;            // N*8 f16
  float* ad1 = ws + off; off += (size_t)N * 8;
  float4* nd2 = (float4*)(ws + off); off += (size_t)N * 4;
  int* deg    = (int*)(ws + off); off += (size_t)N;
  int* rowptr = (int*)(ws + off); off += (size_t)N;
  int* bsum   = (int*)(ws + off); off += 256;
  int* srt    = (int*)(ws + off); off += (size_t)E2;
  int* lrank  = (int*)(ws + off); off += (size_t)E2;
  ushort* Wg  = (ushort*)(ws + off); off += 144 * 64;            // 144*128 bf16

  // prep (also zeroes deg) must run before k_gh
  const int prep_blocks = max((128 * 128 + 128 * 16 + 255) / 256, (N + 255) / 256);
  k_prep<<<prep_blocks, 256, 0, stream>>>(W1, ats1, atd1, Wg, deg, N);

  // GEMM1 + edge histogram in ONE heterogeneous launch (independent work)
  const int GB = (N + 63) / 64;
  const int HB = (E2 + 255) / 256;
  k_gh<<<GB + HB, 256, 0, stream>>>(x, Wg, h1f, as1h, ad1, N, GB, ei, E, deg, lrank);

  // CSR scan + atomic-free place
  k_scan1<<<nb, 256, 0, stream>>>(deg, rowptr, bsum, N);
  k_scan2<<<1, 256, 0, stream>>>(bsum, nb);
  k_scan3<<<(N + 255) / 256, 256, 0, stream>>>(rowptr, bsum, N);
  k_place<<<(E2 + 255) / 256, 256, 0, stream>>>(ei, E, N, rowptr, lrank, srt);

  // fused layer-1 softmax+aggregate+ELU+GEMM2+att dots (4 nodes/wave, unroll-4)
  k_agg1f<<<(N + 15) / 16, 256, 0, stream>>>(rowptr, deg, srt, as1h, ad1, h1f,
                                             b1, W2, ats2, atd2, nd2, N);

  // fused layer-2
  k_agg2f<<<(N + 15) / 16, 256, 0, stream>>>(rowptr, deg, srt, nd2, b2, out, N);
}